// Round 3
// baseline (221.614 us; speedup 1.0000x reference)
//
#include <hip/hip_runtime.h>
#include <hip/hip_bf16.h>

#define N_NODES 100000
#define N_EDGES 3200000
#define N_QUADS (N_EDGES / 4)            // 800000

// ---- bucketing geometry ----
#define P_PARTS 8
#define PART    16384                    // pow2: bucket = dst >> 14 ; 8*16384 = 131072 >= N
#define PART_SH 14

// ---- count/append pass geometry ----
#define CNT_BLOCKS 512
#define CNT_T      512                   // 8 waves/block
#define CNT_WAVES  (CNT_BLOCKS * (CNT_T / 64))   // 4096
#define QPW        ((N_QUADS + CNT_WAVES - 1) / CNT_WAVES)  // 196 quads per wave

// ---- hist pass geometry ----
#define HB_PER_BUCKET 64
#define HIST_BLOCKS   (P_PARTS * HB_PER_BUCKET)  // 512
#define T_HIST        1024               // 16 waves; 64KB LDS -> 2 blocks/CU

// ---------------- workspace layout (bytes) ----------------
#define OFF_STATS  0         // double[5]  (zeroed)
#define OFF_BB     64        // int[9] bucket bases (written by scan)
#define OFF_DEG    1024      // float[100000] (zeroed)          -> 401024
#define OFF_ACC    401024    // float[100000]                   -> 801024
#define OFF_COUNTS 401024    // int[32768] overlay on ACC (dead before encoder writes ACC)
#define OFF_BASES  532096    // int[32768] overlay on ACC       -> 663168 <= 801024  OK
#define OFF_DINV   801024    // float[100000]                   -> 1201024
#define OFF_GS     1201024   // float[100000]                   -> 1601024
#define OFF_SRCB   1601024   // int[N_EDGES] 12.8MB             -> 14401024
#define OFF_DSTB   14401024  // int[N_EDGES] 12.8MB             -> 27201024 total (< 27.22MB prior footprint)

// per-wave int64-vs-int32 detection: high words of first 64 int64 slots
__device__ __forceinline__ bool detect_is64(const void* ei) {
    const int* p = (const int*)ei;
    int lane = threadIdx.x & 63;
    int hi = p[2 * lane + 1];
    unsigned long long m = __ballot(hi != 0);
    return m == 0ull;  // wave-uniform
}

// ---- K1: per-wave bucket counts (dst only) + BN stats ----
__global__ __launch_bounds__(CNT_T, 4) void count_stats_kernel(
        const float* __restrict__ x, const void* __restrict__ ei,
        double* __restrict__ stats, int* __restrict__ counts) {
    bool is64 = detect_is64(ei);
    int lane = threadIdx.x & 63;
    int wg = blockIdx.x * (CNT_T / 64) + (threadIdx.x >> 6);
    int q0 = wg * QPW;
    int q1 = min(q0 + QPW, N_QUADS);
    unsigned c0 = 0, c1 = 0, c2 = 0, c3 = 0, c4 = 0, c5 = 0, c6 = 0, c7 = 0;

    for (int qq = q0; qq < q1; qq += 64) {
        int q = qq + lane;
        bool act = q < q1;
        int4 d4 = make_int4(-1, -1, -1, -1);
        if (act) {
            if (is64) {
                const long long* dstp = (const long long*)ei + N_EDGES;
                longlong2 d01 = ((const longlong2*)dstp)[2 * q];
                longlong2 d23 = ((const longlong2*)dstp)[2 * q + 1];
                d4 = make_int4((int)d01.x, (int)d01.y, (int)d23.x, (int)d23.y);
            } else {
                d4 = ((const int4*)((const int*)ei + N_EDGES))[q];
            }
        }
        unsigned p0 = act ? ((unsigned)d4.x >> PART_SH) : 0xFFu;
        unsigned p1 = act ? ((unsigned)d4.y >> PART_SH) : 0xFFu;
        unsigned p2 = act ? ((unsigned)d4.z >> PART_SH) : 0xFFu;
        unsigned p3 = act ? ((unsigned)d4.w >> PART_SH) : 0xFFu;
#define CNT1(B, C) C += (unsigned)__popcll(__ballot(p0 == (B))) + (unsigned)__popcll(__ballot(p1 == (B))) \
                      + (unsigned)__popcll(__ballot(p2 == (B))) + (unsigned)__popcll(__ballot(p3 == (B)));
        CNT1(0u, c0) CNT1(1u, c1) CNT1(2u, c2) CNT1(3u, c3)
        CNT1(4u, c4) CNT1(5u, c5) CNT1(6u, c6) CNT1(7u, c7)
#undef CNT1
    }
    if (lane == 0) {
        counts[0 * CNT_WAVES + wg] = (int)c0;
        counts[1 * CNT_WAVES + wg] = (int)c1;
        counts[2 * CNT_WAVES + wg] = (int)c2;
        counts[3 * CNT_WAVES + wg] = (int)c3;
        counts[4 * CNT_WAVES + wg] = (int)c4;
        counts[5 * CNT_WAVES + wg] = (int)c5;
        counts[6 * CNT_WAVES + wg] = (int)c6;
        counts[7 * CNT_WAVES + wg] = (int)c7;
    }

    // ---- BN stats over x (blocks covering node range only) ----
    if (blockIdx.x * CNT_T < N_NODES) {
        __shared__ double sh[5][CNT_T / 64];
        int n = blockIdx.x * CNT_T + threadIdx.x;
        double a0 = 0, a1 = 0, a2 = 0, a3 = 0, a4 = 0;
        if (n < N_NODES) {
            float2 v = ((const float2*)x)[n];
            double x0 = v.x, x1 = v.y;
            a0 = x0; a1 = x1; a2 = x0 * x0; a3 = x1 * x1; a4 = x0 * x1;
        }
        for (int off = 32; off; off >>= 1) {
            a0 += __shfl_down(a0, off);
            a1 += __shfl_down(a1, off);
            a2 += __shfl_down(a2, off);
            a3 += __shfl_down(a3, off);
            a4 += __shfl_down(a4, off);
        }
        int w = threadIdx.x >> 6;
        if ((threadIdx.x & 63) == 0) {
            sh[0][w] = a0; sh[1][w] = a1; sh[2][w] = a2; sh[3][w] = a3; sh[4][w] = a4;
        }
        __syncthreads();
        if (threadIdx.x == 0) {
            double t0 = 0, t1 = 0, t2 = 0, t3 = 0, t4 = 0;
            for (int i = 0; i < CNT_T / 64; i++) {
                t0 += sh[0][i]; t1 += sh[1][i]; t2 += sh[2][i]; t3 += sh[3][i]; t4 += sh[4][i];
            }
            atomicAdd(&stats[0], t0);
            atomicAdd(&stats[1], t1);
            atomicAdd(&stats[2], t2);
            atomicAdd(&stats[3], t3);
            atomicAdd(&stats[4], t4);
        }
    }
}

// ---- K2: exclusive scan of counts[8][CNT_WAVES] (bucket-major) -> bases, bucket_base ----
__global__ __launch_bounds__(1024) void scan_kernel(const int* __restrict__ counts,
                                                    int* __restrict__ bases,
                                                    int* __restrict__ bucket_base) {
    const int M = P_PARTS * CNT_WAVES;   // 32768
    const int PER = M / 1024;            // 32
    int t = threadIdx.x;
    int lane = t & 63;
    int local[PER];
    int sum = 0;
#pragma unroll
    for (int j = 0; j < PER; j++) { local[j] = counts[t * PER + j]; sum += local[j]; }
    // inclusive wave scan of per-thread sums
    int inc = sum;
    for (int off = 1; off < 64; off <<= 1) {
        int n = __shfl_up(inc, off);
        if (lane >= off) inc += n;
    }
    __shared__ int wsum[16];
    __shared__ int wbase[16];
    int w = t >> 6;
    if (lane == 63) wsum[w] = inc;
    __syncthreads();
    if (t == 0) {
        int r = 0;
        for (int k = 0; k < 16; k++) { wbase[k] = r; r += wsum[k]; }
    }
    __syncthreads();
    int base = wbase[w] + (inc - sum);   // exclusive prefix for this thread's first element
    int run = base;
#pragma unroll
    for (int j = 0; j < PER; j++) { bases[t * PER + j] = run; run += local[j]; }
    // bucket b starts at linear index b*CNT_WAVES = b*4096 -> owner thread t = b*128 (j==0)
    if ((t & 127) == 0 && (t >> 7) < P_PARTS) bucket_base[t >> 7] = base;
    if (t == 1023) bucket_base[P_PARTS] = run;   // grand total == N_EDGES
}

// ---- K3: append edges into dst-range buckets (atomic-free, per-wave cursors) ----
__global__ __launch_bounds__(CNT_T, 4) void append_kernel(
        const void* __restrict__ ei, const int* __restrict__ bases,
        int* __restrict__ src_b, int* __restrict__ dst_b) {
    bool is64 = detect_is64(ei);
    int lane = threadIdx.x & 63;
    unsigned long long lt = (1ull << lane) - 1ull;
    int wg = blockIdx.x * (CNT_T / 64) + (threadIdx.x >> 6);
    int cur0 = bases[0 * CNT_WAVES + wg];
    int cur1 = bases[1 * CNT_WAVES + wg];
    int cur2 = bases[2 * CNT_WAVES + wg];
    int cur3 = bases[3 * CNT_WAVES + wg];
    int cur4 = bases[4 * CNT_WAVES + wg];
    int cur5 = bases[5 * CNT_WAVES + wg];
    int cur6 = bases[6 * CNT_WAVES + wg];
    int cur7 = bases[7 * CNT_WAVES + wg];
    int q0 = wg * QPW;
    int q1 = min(q0 + QPW, N_QUADS);

    for (int qq = q0; qq < q1; qq += 64) {
        int q = qq + lane;
        bool act = q < q1;
        int4 s4 = make_int4(0, 0, 0, 0);
        int4 d4 = make_int4(-1, -1, -1, -1);
        if (act) {
            if (is64) {
                const long long* srcp = (const long long*)ei;
                const long long* dstp = srcp + N_EDGES;
                longlong2 s01 = ((const longlong2*)srcp)[2 * q];
                longlong2 s23 = ((const longlong2*)srcp)[2 * q + 1];
                longlong2 d01 = ((const longlong2*)dstp)[2 * q];
                longlong2 d23 = ((const longlong2*)dstp)[2 * q + 1];
                s4 = make_int4((int)s01.x, (int)s01.y, (int)s23.x, (int)s23.y);
                d4 = make_int4((int)d01.x, (int)d01.y, (int)d23.x, (int)d23.y);
            } else {
                s4 = ((const int4*)((const int*)ei))[q];
                d4 = ((const int4*)((const int*)ei + N_EDGES))[q];
            }
        }
#define BS(B, CUR) { unsigned long long m = __ballot(p == (B)); \
        if (p == (B)) { int pos = (CUR) + (int)__popcll(m & lt); src_b[pos] = sv; dst_b[pos] = dv; } \
        (CUR) += (int)__popcll(m); }
#define SUBR(SV, DV) { int sv = (SV); int dv = (DV); \
        unsigned p = act ? ((unsigned)dv >> PART_SH) : 0xFFu; \
        BS(0u, cur0) BS(1u, cur1) BS(2u, cur2) BS(3u, cur3) \
        BS(4u, cur4) BS(5u, cur5) BS(6u, cur6) BS(7u, cur7) }
        SUBR(s4.x, d4.x)
        SUBR(s4.y, d4.y)
        SUBR(s4.z, d4.z)
        SUBR(s4.w, d4.w)
#undef SUBR
#undef BS
    }
}

// ---- K4: bucketed degree histogram (each edge touched once, dense lanes) ----
__global__ __launch_bounds__(T_HIST, 8) void deg_hist_kernel(
        const int* __restrict__ dst_b, const int* __restrict__ bucket_base,
        float* __restrict__ degf) {
    __shared__ float hist[PART];
    int b = blockIdx.x >> 6;             // HB_PER_BUCKET = 64
    int sub = blockIdx.x & 63;
    int start = bucket_base[b], end = bucket_base[b + 1];
    int len = end - start;
    if (len <= 0) return;
    int chunk = (len + HB_PER_BUCKET - 1) >> 6;
    int e0 = start + sub * chunk;
    int e1 = min(e0 + chunk, end);
    if (e0 >= e1) return;

    for (int i = threadIdx.x; i < PART; i += T_HIST) hist[i] = 0.f;
    __syncthreads();
    int base = b << PART_SH;
    for (int i = e0 + threadIdx.x; i < e1; i += T_HIST)
        atomicAdd(&hist[dst_b[i] - base], 1.0f);
    __syncthreads();
    for (int i = threadIdx.x; i < PART; i += T_HIST) {
        float v = hist[i];
        int n = base + i;
        if (v != 0.f && n < N_NODES) unsafeAtomicAdd(&degf[n], v);
    }
}

// ---- K5: encoder (unchanged math): gs[n] = dinv * (GB + sum_c PReLU(Ax0+Bx1+C) U[c]) ----
__global__ void encoder_kernel(const float* __restrict__ x,
                               const double* __restrict__ stats,
                               const float* __restrict__ w1, const float* __restrict__ b1,
                               const float* __restrict__ gamma, const float* __restrict__ beta,
                               const float* __restrict__ prelu_a,
                               const float* __restrict__ w2, const float* __restrict__ b2,
                               const float* __restrict__ gcn_w, const float* __restrict__ wb,
                               const float* __restrict__ degf,
                               float* __restrict__ dinv, float* __restrict__ gs,
                               float* __restrict__ acc) {
    __shared__ float sA[32], sB[32], sC[32], sV[32], sU[32];
    __shared__ float sGB;
    if (threadIdx.x < 32) {
        int c = threadIdx.x;
        double invN = 1.0 / (double)N_NODES;
        double m0 = stats[0] * invN, m1 = stats[1] * invN;
        double e00 = stats[2] * invN, e11 = stats[3] * invN, e01 = stats[4] * invN;
        double a = w1[2 * c], b = w1[2 * c + 1], t = b1[c];
        double meanH = a * m0 + b * m1 + t;
        double eh2 = a * a * e00 + b * b * e11 + 2.0 * a * b * e01 +
                     2.0 * t * (a * m0 + b * m1) + t * t;
        double var = eh2 - meanH * meanH;
        double inv = 1.0 / sqrt(var + 1e-5);
        float sc = (float)((double)gamma[c] * inv);
        float shift = beta[c] - (float)meanH * sc;
        sA[c] = (float)a * sc;
        sB[c] = (float)b * sc;
        sC[c] = (float)t * sc + shift;
        float vc = 0.f;
        for (int j = 0; j < 32; j++) vc += wb[j] * gcn_w[j * 32 + c];
        sV[c] = vc;
        float gb = b2[c] * vc;
        for (int off = 16; off; off >>= 1) gb += __shfl_down(gb, off, 32);
        if (c == 0) sGB = gb;
    }
    __syncthreads();
    if (threadIdx.x < 32) {
        float u = 0.f;
        for (int c = 0; c < 32; c++) u += sV[c] * w2[c * 32 + threadIdx.x];
        sU[threadIdx.x] = u;
    }
    __syncthreads();
    float alpha = prelu_a[0];
    int n = blockIdx.x * blockDim.x + threadIdx.x;
    if (n < N_NODES) {
        float2 xv = ((const float2*)x)[n];
        float g = sGB;
#pragma unroll
        for (int c = 0; c < 32; c++) {
            float hb = sA[c] * xv.x + sB[c] * xv.y + sC[c];
            float pc = hb >= 0.f ? hb : alpha * hb;
            g += pc * sU[c];
        }
        float di = rsqrtf(degf[n] + 1.0f);
        float gg = di * g;
        dinv[n] = di;
        gs[n] = gg;
        acc[n] = gg;  // self-loop term; finalize multiplies by dinv
    }
}

// ---- K6: bucketed scatter (dense unconditional gathers, 2-way MLP unroll) ----
__global__ __launch_bounds__(T_HIST, 8) void scatter_kernel(
        const int* __restrict__ src_b, const int* __restrict__ dst_b,
        const int* __restrict__ bucket_base,
        const float* __restrict__ gs, float* __restrict__ acc) {
    __shared__ float hist[PART];
    int b = blockIdx.x >> 6;
    int sub = blockIdx.x & 63;
    int start = bucket_base[b], end = bucket_base[b + 1];
    int len = end - start;
    if (len <= 0) return;
    int chunk = (len + HB_PER_BUCKET - 1) >> 6;
    int e0 = start + sub * chunk;
    int e1 = min(e0 + chunk, end);
    if (e0 >= e1) return;

    for (int i = threadIdx.x; i < PART; i += T_HIST) hist[i] = 0.f;
    __syncthreads();
    int base = b << PART_SH;
    int i = e0 + threadIdx.x;
    for (; i + T_HIST < e1; i += 2 * T_HIST) {
        int s0 = src_b[i];
        int d0 = dst_b[i];
        int s1 = src_b[i + T_HIST];
        int d1 = dst_b[i + T_HIST];
        float g0 = gs[s0];
        float g1 = gs[s1];
        atomicAdd(&hist[d0 - base], g0);
        atomicAdd(&hist[d1 - base], g1);
    }
    if (i < e1) {
        int s = src_b[i], d = dst_b[i];
        atomicAdd(&hist[d - base], gs[s]);
    }
    __syncthreads();
    for (int k = threadIdx.x; k < PART; k += T_HIST) {
        float v = hist[k];
        int n = base + k;
        if (v != 0.f && n < N_NODES) unsafeAtomicAdd(&acc[n], v);
    }
}

// ---- K7: finalize: out = dinv*acc + const ----
__global__ void finalize_kernel(const float* __restrict__ dinv, const float* __restrict__ acc,
                                const float* __restrict__ gcn_b, const float* __restrict__ wb,
                                const float* __restrict__ bb, float* __restrict__ out) {
    __shared__ float scc;
    if (threadIdx.x < 32) {
        float pv = wb[threadIdx.x] * gcn_b[threadIdx.x];
        for (int off = 16; off; off >>= 1) pv += __shfl_down(pv, off, 32);
        if (threadIdx.x == 0) scc = pv + bb[0];
    }
    __syncthreads();
    int n = blockIdx.x * blockDim.x + threadIdx.x;
    if (n < N_NODES) out[n] = dinv[n] * acc[n] + scc;
}

extern "C" void kernel_launch(void* const* d_in, const int* in_sizes, int n_in,
                              void* d_out, int out_size, void* d_ws, size_t ws_size,
                              hipStream_t stream) {
    const float* x       = (const float*)d_in[0];
    const void*  ei      = d_in[1];
    const float* w1      = (const float*)d_in[2];
    const float* b1      = (const float*)d_in[3];
    const float* bn_g    = (const float*)d_in[4];
    const float* bn_b    = (const float*)d_in[5];
    const float* prelu_a = (const float*)d_in[6];
    const float* w2      = (const float*)d_in[7];
    const float* b2      = (const float*)d_in[8];
    const float* gcn_w   = (const float*)d_in[9];
    const float* gcn_b   = (const float*)d_in[10];
    const float* wb      = (const float*)d_in[11];
    const float* bb      = (const float*)d_in[12];
    float* out = (float*)d_out;

    char* base = (char*)d_ws;
    double* stats  = (double*)(base + OFF_STATS);
    int*    bb_ws  = (int*)(base + OFF_BB);
    float*  degf   = (float*)(base + OFF_DEG);
    float*  acc    = (float*)(base + OFF_ACC);
    int*    counts = (int*)(base + OFF_COUNTS);   // overlays acc (dead before encoder)
    int*    bases  = (int*)(base + OFF_BASES);    // overlays acc (dead before encoder)
    float*  dinv   = (float*)(base + OFF_DINV);
    float*  gs     = (float*)(base + OFF_GS);
    int*    src_b  = (int*)(base + OFF_SRCB);
    int*    dst_b  = (int*)(base + OFF_DSTB);

    // zero stats + bucket_base + degf (single contiguous region)
    hipMemsetAsync(d_ws, 0, OFF_DEG + N_NODES * 4, stream);

    count_stats_kernel<<<CNT_BLOCKS, CNT_T, 0, stream>>>(x, ei, stats, counts);
    scan_kernel<<<1, 1024, 0, stream>>>(counts, bases, bb_ws);
    append_kernel<<<CNT_BLOCKS, CNT_T, 0, stream>>>(ei, bases, src_b, dst_b);
    deg_hist_kernel<<<HIST_BLOCKS, T_HIST, 0, stream>>>(dst_b, bb_ws, degf);
    encoder_kernel<<<(N_NODES + 255) / 256, 256, 0, stream>>>(
        x, stats, w1, b1, bn_g, bn_b, prelu_a, w2, b2, gcn_w, wb, degf, dinv, gs, acc);
    scatter_kernel<<<HIST_BLOCKS, T_HIST, 0, stream>>>(src_b, dst_b, bb_ws, gs, acc);
    finalize_kernel<<<(N_NODES + 255) / 256, 256, 0, stream>>>(dinv, acc, gcn_b, wb, bb, out);
}